// Round 1
// baseline (284.140 us; speedup 1.0000x reference)
//
#include <hip/hip_runtime.h>

#define N_ATOMS 50000
#define N_BONDS 100000
#define BATCH   16
#define N3      150000   // N_ATOMS*3 (rows of w_out, per-batch output elems)

// workspace layout (float offsets)
#define X_OFF   0                      // 16*256 = 4096 floats
#define MC_OFF  4096                   // 12 floats (M row-major 9, c 3)
#define DEG_OFF 4112                   // 50000 floats
#define HT_OFF  54144                  // N_ATOMS*48 = 2,400,000 floats (h transposed [n][b*3+d])
#define NB_OFF  2454144                // N_ATOMS*48 floats (nb_sum, optional in ws)

// ---------------- tiny MLP head: x[16][256] ----------------
__global__ void mlp_head_kernel(const float* __restrict__ alpha,
    const float* __restrict__ w_in, const float* __restrict__ b_in,
    const float* __restrict__ w1a, const float* __restrict__ b1a,
    const float* __restrict__ w1b, const float* __restrict__ b1b,
    const float* __restrict__ w2a, const float* __restrict__ b2a,
    const float* __restrict__ w2b, const float* __restrict__ b2b,
    float* __restrict__ x_out)
{
    __shared__ float xs[256];
    __shared__ float ts[256];
    const int b = blockIdx.x;
    const int j = threadIdx.x;

    float v = fmaxf(w_in[j] * alpha[b] + b_in[j], 0.f);
    xs[j] = v;
    __syncthreads();

    // ResBlock 1
    {
        float acc = b1a[j];
        const float4* wr = reinterpret_cast<const float4*>(w1a + j * 256);
        #pragma unroll 8
        for (int k4 = 0; k4 < 64; ++k4) {
            float4 w = wr[k4];
            acc += w.x * xs[4*k4] + w.y * xs[4*k4+1] + w.z * xs[4*k4+2] + w.w * xs[4*k4+3];
        }
        ts[j] = fmaxf(acc, 0.f);
        __syncthreads();

        acc = b1b[j] + xs[j];
        wr = reinterpret_cast<const float4*>(w1b + j * 256);
        #pragma unroll 8
        for (int k4 = 0; k4 < 64; ++k4) {
            float4 w = wr[k4];
            acc += w.x * ts[4*k4] + w.y * ts[4*k4+1] + w.z * ts[4*k4+2] + w.w * ts[4*k4+3];
        }
        v = fmaxf(acc, 0.f);
        __syncthreads();
        xs[j] = v;
        __syncthreads();
    }
    // ResBlock 2
    {
        float acc = b2a[j];
        const float4* wr = reinterpret_cast<const float4*>(w2a + j * 256);
        #pragma unroll 8
        for (int k4 = 0; k4 < 64; ++k4) {
            float4 w = wr[k4];
            acc += w.x * xs[4*k4] + w.y * xs[4*k4+1] + w.z * xs[4*k4+2] + w.w * xs[4*k4+3];
        }
        ts[j] = fmaxf(acc, 0.f);
        __syncthreads();

        acc = b2b[j] + xs[j];
        wr = reinterpret_cast<const float4*>(w2b + j * 256);
        #pragma unroll 8
        for (int k4 = 0; k4 < 64; ++k4) {
            float4 w = wr[k4];
            acc += w.x * ts[4*k4] + w.y * ts[4*k4+1] + w.z * ts[4*k4+2] + w.w * ts[4*k4+3];
        }
        v = fmaxf(acc, 0.f);
    }
    x_out[b * 256 + j] = v;
}

// ---------------- collapse msg->upd into 3x3 affine: M, c ----------------
__global__ void mc_kernel(const float* __restrict__ msg_w, const float* __restrict__ msg_b,
                          const float* __restrict__ upd_w, const float* __restrict__ upd_b,
                          float* __restrict__ mc)
{
    int t = threadIdx.x;
    if (t < 9) {
        int d = t / 3, dp = t % 3;
        float s = 0.f;
        for (int k = 0; k < 128; ++k) s += upd_w[d*128 + k] * msg_w[k*3 + dp];
        mc[t] = s;                      // M[d][dp]
    } else if (t < 12) {
        int d = t - 9;
        float s = upd_b[d];
        for (int k = 0; k < 128; ++k) s += upd_w[d*128 + k] * msg_b[k];
        mc[9 + d] = s;                  // c[d]
    }
}

// ---------------- degree ----------------
__global__ void deg_kernel(const int* __restrict__ bonds, float* __restrict__ deg)
{
    int e = blockIdx.x * blockDim.x + threadIdx.x;
    if (e >= N_BONDS) return;
    atomicAdd(deg + bonds[2*e],     1.f);
    atomicAdd(deg + bonds[2*e + 1], 1.f);
}

// ---------------- transpose positions (b,n,d) -> h_t[n][b*3+d] ----------------
__global__ void transpose_in_kernel(const float* __restrict__ pos, float* __restrict__ h_t)
{
    int t = blockIdx.x * blockDim.x + threadIdx.x;
    if (t >= N_ATOMS * 48) return;
    int n = t / 48, c = t % 48;
    int b = c / 3, d = c % 3;
    h_t[t] = pos[(b * N_ATOMS + n) * 3 + d];
}

// ---------------- scatter: nb[dst] += h[src], both directions ----------------
__global__ void scatter_kernel(const int* __restrict__ bonds,
                               const float* __restrict__ h_t, float* __restrict__ nb_t)
{
    int t = blockIdx.x * 192 + threadIdx.x;
    int e = t / 48, c = t % 48;
    if (e >= N_BONDS) return;
    int a  = bonds[2*e];
    int bb = bonds[2*e + 1];
    float va = h_t[a  * 48 + c];
    float vb = h_t[bb * 48 + c];
    atomicAdd(nb_t + bb * 48 + c, va);
    atomicAdd(nb_t + a  * 48 + c, vb);
}

// ---------------- per-atom affine update: h += M*(nb/deg)+c or upd_b ----------------
__global__ void update_kernel(const float* __restrict__ nb_t, const float* __restrict__ deg,
                              const float* __restrict__ mc, const float* __restrict__ upd_b,
                              float* __restrict__ h_t)
{
    int t = blockIdx.x * blockDim.x + threadIdx.x;
    if (t >= N_ATOMS * BATCH) return;
    int n = t >> 4;
    int base = n * 48 + (t & 15) * 3;
    float dg = deg[n];
    float d0, d1, d2;
    if (dg > 0.f) {
        float inv = 1.f / dg;           // safe_deg == deg when deg>0
        float m0 = nb_t[base] * inv, m1 = nb_t[base+1] * inv, m2 = nb_t[base+2] * inv;
        d0 = mc[9]  + mc[0]*m0 + mc[1]*m1 + mc[2]*m2;
        d1 = mc[10] + mc[3]*m0 + mc[4]*m1 + mc[5]*m2;
        d2 = mc[11] + mc[6]*m0 + mc[7]*m1 + mc[8]*m2;
    } else {
        d0 = upd_b[0]; d1 = upd_b[1]; d2 = upd_b[2];
    }
    h_t[base]     += d0;
    h_t[base + 1] += d1;
    h_t[base + 2] += d2;
}

// ---------------- fused output: standard GEMM + b_out + go-affine(h) ----------------
__global__ __launch_bounds__(128) void out_kernel(
    const float* __restrict__ w_out, const float* __restrict__ b_out,
    const float* __restrict__ x, const float* __restrict__ h_t,
    const float* __restrict__ go_w, const float* __restrict__ go_b,
    float* __restrict__ out)
{
    int r = blockIdx.x * 128 + threadIdx.x;
    if (r >= N3) return;

    float acc[16];
    #pragma unroll
    for (int b = 0; b < 16; ++b) acc[b] = 0.f;

    const float4* wr = reinterpret_cast<const float4*>(w_out + (size_t)r * 256);
    #pragma unroll 4
    for (int k4 = 0; k4 < 64; ++k4) {
        float4 w = wr[k4];
        #pragma unroll
        for (int b = 0; b < 16; ++b) {
            // uniform address -> scalar (s_load) path; no LDS needed
            float4 xv = reinterpret_cast<const float4*>(x + b * 256)[k4];
            acc[b] += w.x * xv.x + w.y * xv.y + w.z * xv.z + w.w * xv.w;
        }
    }

    int n = r / 3, d = r % 3;
    float g0 = go_w[d*3 + 0], g1 = go_w[d*3 + 1], g2 = go_w[d*3 + 2];
    float gb = go_b[d] + b_out[r];
    const float* hb = h_t + n * 48;
    #pragma unroll
    for (int b = 0; b < 16; ++b) {
        float g = gb + g0 * hb[b*3] + g1 * hb[b*3 + 1] + g2 * hb[b*3 + 2];
        out[b * N3 + r] = acc[b] + g;
    }
}

extern "C" void kernel_launch(void* const* d_in, const int* in_sizes, int n_in,
                              void* d_out, int out_size, void* d_ws, size_t ws_size,
                              hipStream_t stream)
{
    const float* alpha = (const float*)d_in[0];
    const float* pos   = (const float*)d_in[1];
    const int*   bonds = (const int*)  d_in[2];
    const float* w_in  = (const float*)d_in[3];
    const float* b_in  = (const float*)d_in[4];
    const float* w1a   = (const float*)d_in[5];
    const float* b1a   = (const float*)d_in[6];
    const float* w1b   = (const float*)d_in[7];
    const float* b1b   = (const float*)d_in[8];
    const float* w2a   = (const float*)d_in[9];
    const float* b2a   = (const float*)d_in[10];
    const float* w2b   = (const float*)d_in[11];
    const float* b2b   = (const float*)d_in[12];
    const float* w_out = (const float*)d_in[13];
    const float* b_out = (const float*)d_in[14];
    const float* msg_w = (const float*)d_in[15];
    const float* msg_b = (const float*)d_in[16];
    const float* upd_w = (const float*)d_in[17];
    const float* upd_b = (const float*)d_in[18];
    const float* go_w  = (const float*)d_in[19];
    const float* go_b  = (const float*)d_in[20];

    float* out = (float*)d_out;
    float* ws  = (float*)d_ws;

    float* x    = ws + X_OFF;
    float* mc   = ws + MC_OFF;
    float* deg  = ws + DEG_OFF;
    float* h_t  = ws + HT_OFF;
    // nb_sum scratch: prefer ws, fall back to d_out (exactly N_ATOMS*48 floats)
    size_t need_full = (size_t)(NB_OFF + N_ATOMS * 48) * sizeof(float);
    float* nb_t = (ws_size >= need_full) ? (ws + NB_OFF) : out;

    hipMemsetAsync(deg, 0, N_ATOMS * sizeof(float), stream);
    deg_kernel<<<(N_BONDS + 255) / 256, 256, 0, stream>>>(bonds, deg);
    mlp_head_kernel<<<16, 256, 0, stream>>>(alpha, w_in, b_in,
                                            w1a, b1a, w1b, b1b,
                                            w2a, b2a, w2b, b2b, x);
    mc_kernel<<<1, 64, 0, stream>>>(msg_w, msg_b, upd_w, upd_b, mc);
    transpose_in_kernel<<<(N_ATOMS * 48 + 255) / 256, 256, 0, stream>>>(pos, h_t);

    for (int it = 0; it < 2; ++it) {
        hipMemsetAsync(nb_t, 0, (size_t)N_ATOMS * 48 * sizeof(float), stream);
        scatter_kernel<<<25000, 192, 0, stream>>>(bonds, h_t, nb_t);
        update_kernel<<<(N_ATOMS * BATCH + 255) / 256, 256, 0, stream>>>(nb_t, deg, mc, upd_b, h_t);
    }

    out_kernel<<<(N3 + 127) / 128, 128, 0, stream>>>(w_out, b_out, x, h_t, go_w, go_b, out);
}

// Round 2
// 278.494 us; speedup vs baseline: 1.0203x; 1.0203x over previous
//
#include <hip/hip_runtime.h>

#define N_ATOMS 50000
#define N_BONDS 100000
#define BATCH   16
#define N3      150000   // N_ATOMS*3

// ---- fast-path workspace layout (4-byte element offsets) ----
#define X_OFF    0            // 4096 floats
#define MC_OFF   4096         // 16 floats (M 9, c 3)
#define DEGI_OFF 4112         // 50000 ints
#define OFFS_OFF 54112        // 50001 ints (+pad)
#define CUR_OFF  104128       // 50000 ints
#define ADJ_OFF  154128       // 200000 ints
#define HA_OFF   354128       // 2,400,000 floats
#define HB_OFF   2754128      // 2,400,000 floats
#define WS_FAST_BYTES ((size_t)(HB_OFF + 2400000) * 4)

// ---- fallback (round-1) layout ----
#define DEGF_OFF 4112         // 50000 floats
#define HT_OFF   54144        // 2,400,000 floats
#define NB_OFF   2454144      // 2,400,000 floats (optional in ws)

// ---------------- tiny MLP head: x[16][256] ----------------
__global__ void mlp_head_kernel(const float* __restrict__ alpha,
    const float* __restrict__ w_in, const float* __restrict__ b_in,
    const float* __restrict__ w1a, const float* __restrict__ b1a,
    const float* __restrict__ w1b, const float* __restrict__ b1b,
    const float* __restrict__ w2a, const float* __restrict__ b2a,
    const float* __restrict__ w2b, const float* __restrict__ b2b,
    float* __restrict__ x_out)
{
    __shared__ float xs[256];
    __shared__ float ts[256];
    const int b = blockIdx.x;
    const int j = threadIdx.x;

    float v = fmaxf(w_in[j] * alpha[b] + b_in[j], 0.f);
    xs[j] = v;
    __syncthreads();

    {   // ResBlock 1
        float acc = b1a[j];
        const float4* wr = reinterpret_cast<const float4*>(w1a + j * 256);
        #pragma unroll 8
        for (int k4 = 0; k4 < 64; ++k4) {
            float4 w = wr[k4];
            acc += w.x * xs[4*k4] + w.y * xs[4*k4+1] + w.z * xs[4*k4+2] + w.w * xs[4*k4+3];
        }
        ts[j] = fmaxf(acc, 0.f);
        __syncthreads();

        acc = b1b[j] + xs[j];
        wr = reinterpret_cast<const float4*>(w1b + j * 256);
        #pragma unroll 8
        for (int k4 = 0; k4 < 64; ++k4) {
            float4 w = wr[k4];
            acc += w.x * ts[4*k4] + w.y * ts[4*k4+1] + w.z * ts[4*k4+2] + w.w * ts[4*k4+3];
        }
        v = fmaxf(acc, 0.f);
        __syncthreads();
        xs[j] = v;
        __syncthreads();
    }
    {   // ResBlock 2
        float acc = b2a[j];
        const float4* wr = reinterpret_cast<const float4*>(w2a + j * 256);
        #pragma unroll 8
        for (int k4 = 0; k4 < 64; ++k4) {
            float4 w = wr[k4];
            acc += w.x * xs[4*k4] + w.y * xs[4*k4+1] + w.z * xs[4*k4+2] + w.w * xs[4*k4+3];
        }
        ts[j] = fmaxf(acc, 0.f);
        __syncthreads();

        acc = b2b[j] + xs[j];
        wr = reinterpret_cast<const float4*>(w2b + j * 256);
        #pragma unroll 8
        for (int k4 = 0; k4 < 64; ++k4) {
            float4 w = wr[k4];
            acc += w.x * ts[4*k4] + w.y * ts[4*k4+1] + w.z * ts[4*k4+2] + w.w * ts[4*k4+3];
        }
        v = fmaxf(acc, 0.f);
    }
    x_out[b * 256 + j] = v;
}

// ---------------- collapse msg->upd into 3x3 affine: M, c ----------------
__global__ void mc_kernel(const float* __restrict__ msg_w, const float* __restrict__ msg_b,
                          const float* __restrict__ upd_w, const float* __restrict__ upd_b,
                          float* __restrict__ mc)
{
    int t = threadIdx.x;
    if (t < 9) {
        int d = t / 3, dp = t % 3;
        float s = 0.f;
        for (int k = 0; k < 128; ++k) s += upd_w[d*128 + k] * msg_w[k*3 + dp];
        mc[t] = s;
    } else if (t < 12) {
        int d = t - 9;
        float s = upd_b[d];
        for (int k = 0; k < 128; ++k) s += upd_w[d*128 + k] * msg_b[k];
        mc[9 + d] = s;
    }
}

// ---------------- transpose positions (b,n,d) -> h[n][b*3+d] ----------------
__global__ void transpose_in_kernel(const float* __restrict__ pos, float* __restrict__ h_t)
{
    int t = blockIdx.x * blockDim.x + threadIdx.x;
    if (t >= N_ATOMS * 48) return;
    int n = t / 48, c = t % 48;
    int b = c / 3, d = c % 3;
    h_t[t] = pos[(b * N_ATOMS + n) * 3 + d];
}

// ================= CSR fast path =================
__global__ void degi_kernel(const int* __restrict__ bonds, int* __restrict__ deg)
{
    int e = blockIdx.x * blockDim.x + threadIdx.x;
    if (e >= N_BONDS) return;
    atomicAdd(deg + bonds[2*e],     1);
    atomicAdd(deg + bonds[2*e + 1], 1);
}

__global__ __launch_bounds__(1024) void scan_kernel(const int* __restrict__ deg,
                                                    int* __restrict__ offs,
                                                    int* __restrict__ cursor)
{
    __shared__ int part[1024];
    const int tid = threadIdx.x;
    const int C = (N_ATOMS + 1023) / 1024;   // 49
    const int base = tid * C;
    int s = 0;
    for (int i = 0; i < C; ++i) { int idx = base + i; if (idx < N_ATOMS) s += deg[idx]; }
    part[tid] = s;
    __syncthreads();
    for (int off = 1; off < 1024; off <<= 1) {
        int v = part[tid];
        int add = (tid >= off) ? part[tid - off] : 0;
        __syncthreads();
        part[tid] = v + add;
        __syncthreads();
    }
    int run = (tid == 0) ? 0 : part[tid - 1];
    for (int i = 0; i < C; ++i) {
        int idx = base + i;
        if (idx < N_ATOMS) { offs[idx] = run; cursor[idx] = run; run += deg[idx]; }
    }
    if (tid == 1023) offs[N_ATOMS] = 2 * N_BONDS;
}

__global__ void fill_kernel(const int* __restrict__ bonds, int* __restrict__ cursor,
                            int* __restrict__ adj)
{
    int e = blockIdx.x * blockDim.x + threadIdx.x;
    if (e >= N_BONDS) return;
    int a = bonds[2*e], b = bonds[2*e + 1];
    adj[atomicAdd(cursor + b, 1)] = a;
    adj[atomicAdd(cursor + a, 1)] = b;
}

// fused gather + mean + affine + residual: h_out = h_in + M*mean_nb(h_in)+c
__global__ void gather_kernel(const int* __restrict__ offs, const int* __restrict__ adj,
                              const float* __restrict__ mc, const float* __restrict__ upd_b,
                              const float* __restrict__ h_in, float* __restrict__ h_out)
{
    int t = blockIdx.x * blockDim.x + threadIdx.x;
    if (t >= N_ATOMS * BATCH) return;
    int n = t >> 4, b = t & 15;
    int o0 = offs[n], o1 = offs[n + 1];
    int base = n * 48 + b * 3;
    float d0, d1, d2;
    if (o1 > o0) {
        float s0 = 0.f, s1 = 0.f, s2 = 0.f;
        for (int j = o0; j < o1; ++j) {
            const float* hs = h_in + adj[j] * 48 + b * 3;
            s0 += hs[0]; s1 += hs[1]; s2 += hs[2];
        }
        float inv = 1.f / (float)(o1 - o0);
        s0 *= inv; s1 *= inv; s2 *= inv;
        d0 = mc[9]  + mc[0]*s0 + mc[1]*s1 + mc[2]*s2;
        d1 = mc[10] + mc[3]*s0 + mc[4]*s1 + mc[5]*s2;
        d2 = mc[11] + mc[6]*s0 + mc[7]*s1 + mc[8]*s2;
    } else {
        d0 = upd_b[0]; d1 = upd_b[1]; d2 = upd_b[2];
    }
    h_out[base]     = h_in[base]     + d0;
    h_out[base + 1] = h_in[base + 1] + d1;
    h_out[base + 2] = h_in[base + 2] + d2;
}

// ================= fallback (round-1) graph kernels =================
__global__ void degf_kernel(const int* __restrict__ bonds, float* __restrict__ deg)
{
    int e = blockIdx.x * blockDim.x + threadIdx.x;
    if (e >= N_BONDS) return;
    atomicAdd(deg + bonds[2*e],     1.f);
    atomicAdd(deg + bonds[2*e + 1], 1.f);
}

__global__ void scatter_kernel(const int* __restrict__ bonds,
                               const float* __restrict__ h_t, float* __restrict__ nb_t)
{
    int t = blockIdx.x * 192 + threadIdx.x;
    int e = t / 48, c = t % 48;
    if (e >= N_BONDS) return;
    int a  = bonds[2*e];
    int bb = bonds[2*e + 1];
    float va = h_t[a  * 48 + c];
    float vb = h_t[bb * 48 + c];
    atomicAdd(nb_t + bb * 48 + c, va);
    atomicAdd(nb_t + a  * 48 + c, vb);
}

__global__ void update_kernel(const float* __restrict__ nb_t, const float* __restrict__ deg,
                              const float* __restrict__ mc, const float* __restrict__ upd_b,
                              float* __restrict__ h_t)
{
    int t = blockIdx.x * blockDim.x + threadIdx.x;
    if (t >= N_ATOMS * BATCH) return;
    int n = t >> 4;
    int base = n * 48 + (t & 15) * 3;
    float dg = deg[n];
    float d0, d1, d2;
    if (dg > 0.f) {
        float inv = 1.f / dg;
        float m0 = nb_t[base] * inv, m1 = nb_t[base+1] * inv, m2 = nb_t[base+2] * inv;
        d0 = mc[9]  + mc[0]*m0 + mc[1]*m1 + mc[2]*m2;
        d1 = mc[10] + mc[3]*m0 + mc[4]*m1 + mc[5]*m2;
        d2 = mc[11] + mc[6]*m0 + mc[7]*m1 + mc[8]*m2;
    } else {
        d0 = upd_b[0]; d1 = upd_b[1]; d2 = upd_b[2];
    }
    h_t[base]     += d0;
    h_t[base + 1] += d1;
    h_t[base + 2] += d2;
}

// ---------------- fused output: standard GEMM + b_out + go-affine(h) ----------------
// 1 wave per block; x staged in LDS (broadcast reads); w row double-buffered in regs.
__global__ __launch_bounds__(64) void out_kernel(
    const float* __restrict__ w_out, const float* __restrict__ b_out,
    const float* __restrict__ x, const float* __restrict__ h_t,
    const float* __restrict__ go_w, const float* __restrict__ go_b,
    float* __restrict__ out)
{
    __shared__ float4 xs[1024];                 // [b][k4], 16 KiB
    const int tid = threadIdx.x;
    const float4* xv = reinterpret_cast<const float4*>(x);
    #pragma unroll
    for (int i = 0; i < 16; ++i) xs[tid + i * 64] = xv[tid + i * 64];
    __syncthreads();

    const int r = blockIdx.x * 64 + tid;
    if (r >= N3) return;
    const float4* wr = reinterpret_cast<const float4*>(w_out + (size_t)r * 256);

    float acc[16];
    #pragma unroll
    for (int b = 0; b < 16; ++b) acc[b] = 0.f;

    float4 wbuf[4];
    #pragma unroll
    for (int i = 0; i < 4; ++i) wbuf[i] = wr[i];

    #pragma unroll 1
    for (int c = 0; c < 16; ++c) {
        float4 wcur[4];
        #pragma unroll
        for (int i = 0; i < 4; ++i) wcur[i] = wbuf[i];
        if (c < 15) {
            #pragma unroll
            for (int i = 0; i < 4; ++i) wbuf[i] = wr[(c + 1) * 4 + i];
        }
        #pragma unroll
        for (int i = 0; i < 4; ++i) {
            const int k4 = c * 4 + i;
            #pragma unroll
            for (int b = 0; b < 16; ++b) {
                float4 xf = xs[b * 64 + k4];
                acc[b] += wcur[i].x * xf.x + wcur[i].y * xf.y
                        + wcur[i].z * xf.z + wcur[i].w * xf.w;
            }
        }
    }

    const int n = r / 3, d = r - 3 * n;
    const float g0 = go_w[d*3 + 0], g1 = go_w[d*3 + 1], g2 = go_w[d*3 + 2];
    const float gb = go_b[d] + b_out[r];
    const float* hb = h_t + n * 48;
    #pragma unroll
    for (int b = 0; b < 16; ++b) {
        float g = gb + g0 * hb[b*3] + g1 * hb[b*3 + 1] + g2 * hb[b*3 + 2];
        out[b * N3 + r] = acc[b] + g;
    }
}

extern "C" void kernel_launch(void* const* d_in, const int* in_sizes, int n_in,
                              void* d_out, int out_size, void* d_ws, size_t ws_size,
                              hipStream_t stream)
{
    const float* alpha = (const float*)d_in[0];
    const float* pos   = (const float*)d_in[1];
    const int*   bonds = (const int*)  d_in[2];
    const float* w_in  = (const float*)d_in[3];
    const float* b_in  = (const float*)d_in[4];
    const float* w1a   = (const float*)d_in[5];
    const float* b1a   = (const float*)d_in[6];
    const float* w1b   = (const float*)d_in[7];
    const float* b1b   = (const float*)d_in[8];
    const float* w2a   = (const float*)d_in[9];
    const float* b2a   = (const float*)d_in[10];
    const float* w2b   = (const float*)d_in[11];
    const float* b2b   = (const float*)d_in[12];
    const float* w_out = (const float*)d_in[13];
    const float* b_out = (const float*)d_in[14];
    const float* msg_w = (const float*)d_in[15];
    const float* msg_b = (const float*)d_in[16];
    const float* upd_w = (const float*)d_in[17];
    const float* upd_b = (const float*)d_in[18];
    const float* go_w  = (const float*)d_in[19];
    const float* go_b  = (const float*)d_in[20];

    float* out = (float*)d_out;
    float* ws  = (float*)d_ws;
    float* x   = ws + X_OFF;
    float* mc  = ws + MC_OFF;

    mlp_head_kernel<<<16, 256, 0, stream>>>(alpha, w_in, b_in,
                                            w1a, b1a, w1b, b1b,
                                            w2a, b2a, w2b, b2b, x);
    mc_kernel<<<1, 64, 0, stream>>>(msg_w, msg_b, upd_w, upd_b, mc);

    float* h_final;
    if (ws_size >= WS_FAST_BYTES) {
        // -------- CSR fast path --------
        int*   deg_i  = (int*)(ws + DEGI_OFF);
        int*   offs   = (int*)(ws + OFFS_OFF);
        int*   cursor = (int*)(ws + CUR_OFF);
        int*   adj    = (int*)(ws + ADJ_OFF);
        float* hA     = ws + HA_OFF;
        float* hB     = ws + HB_OFF;

        hipMemsetAsync(deg_i, 0, N_ATOMS * sizeof(int), stream);
        degi_kernel<<<(N_BONDS + 255) / 256, 256, 0, stream>>>(bonds, deg_i);
        scan_kernel<<<1, 1024, 0, stream>>>(deg_i, offs, cursor);
        fill_kernel<<<(N_BONDS + 255) / 256, 256, 0, stream>>>(bonds, cursor, adj);
        transpose_in_kernel<<<(N_ATOMS * 48 + 255) / 256, 256, 0, stream>>>(pos, hA);

        gather_kernel<<<(N_ATOMS * BATCH + 255) / 256, 256, 0, stream>>>(offs, adj, mc, upd_b, hA, hB);
        gather_kernel<<<(N_ATOMS * BATCH + 255) / 256, 256, 0, stream>>>(offs, adj, mc, upd_b, hB, hA);
        h_final = hA;
    } else {
        // -------- fallback: round-1 atomic scatter path --------
        float* degf = ws + DEGF_OFF;
        float* h_t  = ws + HT_OFF;
        size_t need_full = (size_t)(NB_OFF + N_ATOMS * 48) * sizeof(float);
        float* nb_t = (ws_size >= need_full) ? (ws + NB_OFF) : out;

        hipMemsetAsync(degf, 0, N_ATOMS * sizeof(float), stream);
        degf_kernel<<<(N_BONDS + 255) / 256, 256, 0, stream>>>(bonds, degf);
        transpose_in_kernel<<<(N_ATOMS * 48 + 255) / 256, 256, 0, stream>>>(pos, h_t);
        for (int it = 0; it < 2; ++it) {
            hipMemsetAsync(nb_t, 0, (size_t)N_ATOMS * 48 * sizeof(float), stream);
            scatter_kernel<<<25000, 192, 0, stream>>>(bonds, h_t, nb_t);
            update_kernel<<<(N_ATOMS * BATCH + 255) / 256, 256, 0, stream>>>(nb_t, degf, mc, upd_b, h_t);
        }
        h_final = h_t;
    }

    out_kernel<<<(N3 + 63) / 64, 64, 0, stream>>>(w_out, b_out, x, h_final, go_w, go_b, out);
}

// Round 3
// 162.526 us; speedup vs baseline: 1.7483x; 1.7135x over previous
//
#include <hip/hip_runtime.h>

#define N_ATOMS 50000
#define N_BONDS 100000
#define BATCH   16
#define N3      150000   // N_ATOMS*3

#define SCAN_BLOCKS ((N_ATOMS + 255) / 256)   // 196

// ---- fast-path workspace layout (4-byte element offsets) ----
#define X_OFF    0            // 4096 floats
#define MC_OFF   4096         // 16 floats (M 9, c 3)
#define DEGI_OFF 4112         // 50000 ints
#define OFFS_OFF 54112        // 50001 ints (+pad to 50016)
#define CUR_OFF  104128       // 50000 ints
#define PART_OFF 154128       // 256 ints
#define ADJ_OFF  154384       // 200000 ints
#define HA_OFF   354384       // 2,400,000 floats
#define HB_OFF   2754384      // 2,400,000 floats
#define WS_FAST_BYTES ((size_t)(HB_OFF + 2400000) * 4)

// ---- fallback (round-1) layout ----
#define DEGF_OFF 4112         // 50000 floats
#define HT_OFF   54144        // 2,400,000 floats
#define NB_OFF   2454144      // 2,400,000 floats (optional in ws)

// ---------------- tiny MLP head: x[16][256] ----------------
__global__ void mlp_head_kernel(const float* __restrict__ alpha,
    const float* __restrict__ w_in, const float* __restrict__ b_in,
    const float* __restrict__ w1a, const float* __restrict__ b1a,
    const float* __restrict__ w1b, const float* __restrict__ b1b,
    const float* __restrict__ w2a, const float* __restrict__ b2a,
    const float* __restrict__ w2b, const float* __restrict__ b2b,
    float* __restrict__ x_out)
{
    __shared__ float xs[256];
    __shared__ float ts[256];
    const int b = blockIdx.x;
    const int j = threadIdx.x;

    float v = fmaxf(w_in[j] * alpha[b] + b_in[j], 0.f);
    xs[j] = v;
    __syncthreads();

    {   // ResBlock 1
        float acc = b1a[j];
        const float4* wr = reinterpret_cast<const float4*>(w1a + j * 256);
        #pragma unroll 8
        for (int k4 = 0; k4 < 64; ++k4) {
            float4 w = wr[k4];
            acc += w.x * xs[4*k4] + w.y * xs[4*k4+1] + w.z * xs[4*k4+2] + w.w * xs[4*k4+3];
        }
        ts[j] = fmaxf(acc, 0.f);
        __syncthreads();

        acc = b1b[j] + xs[j];
        wr = reinterpret_cast<const float4*>(w1b + j * 256);
        #pragma unroll 8
        for (int k4 = 0; k4 < 64; ++k4) {
            float4 w = wr[k4];
            acc += w.x * ts[4*k4] + w.y * ts[4*k4+1] + w.z * ts[4*k4+2] + w.w * ts[4*k4+3];
        }
        v = fmaxf(acc, 0.f);
        __syncthreads();
        xs[j] = v;
        __syncthreads();
    }
    {   // ResBlock 2
        float acc = b2a[j];
        const float4* wr = reinterpret_cast<const float4*>(w2a + j * 256);
        #pragma unroll 8
        for (int k4 = 0; k4 < 64; ++k4) {
            float4 w = wr[k4];
            acc += w.x * xs[4*k4] + w.y * xs[4*k4+1] + w.z * xs[4*k4+2] + w.w * xs[4*k4+3];
        }
        ts[j] = fmaxf(acc, 0.f);
        __syncthreads();

        acc = b2b[j] + xs[j];
        wr = reinterpret_cast<const float4*>(w2b + j * 256);
        #pragma unroll 8
        for (int k4 = 0; k4 < 64; ++k4) {
            float4 w = wr[k4];
            acc += w.x * ts[4*k4] + w.y * ts[4*k4+1] + w.z * ts[4*k4+2] + w.w * ts[4*k4+3];
        }
        v = fmaxf(acc, 0.f);
    }
    x_out[b * 256 + j] = v;
}

// ---------------- collapse msg->upd into 3x3 affine: M, c ----------------
__global__ void mc_kernel(const float* __restrict__ msg_w, const float* __restrict__ msg_b,
                          const float* __restrict__ upd_w, const float* __restrict__ upd_b,
                          float* __restrict__ mc)
{
    int t = threadIdx.x;
    if (t < 9) {
        int d = t / 3, dp = t % 3;
        float s = 0.f;
        for (int k = 0; k < 128; ++k) s += upd_w[d*128 + k] * msg_w[k*3 + dp];
        mc[t] = s;
    } else if (t < 12) {
        int d = t - 9;
        float s = upd_b[d];
        for (int k = 0; k < 128; ++k) s += upd_w[d*128 + k] * msg_b[k];
        mc[9 + d] = s;
    }
}

// ---------------- transpose positions (b,n,d) -> h[n][b*3+d] ----------------
__global__ void transpose_in_kernel(const float* __restrict__ pos, float* __restrict__ h_t)
{
    int t = blockIdx.x * blockDim.x + threadIdx.x;
    if (t >= N_ATOMS * 48) return;
    int n = t / 48, c = t % 48;
    int b = c / 3, d = c % 3;
    h_t[t] = pos[(b * N_ATOMS + n) * 3 + d];
}

// ================= CSR fast path =================
__global__ void degi_kernel(const int* __restrict__ bonds, int* __restrict__ deg)
{
    int e = blockIdx.x * blockDim.x + threadIdx.x;
    if (e >= N_BONDS) return;
    atomicAdd(deg + bonds[2*e],     1);
    atomicAdd(deg + bonds[2*e + 1], 1);
}

// --- hierarchical exclusive scan over deg (3 stages, all parallel) ---
__global__ __launch_bounds__(256) void scan_part_kernel(const int* __restrict__ deg,
                                                        int* __restrict__ part)
{
    __shared__ int sh[256];
    int tid = threadIdx.x;
    int idx = blockIdx.x * 256 + tid;
    sh[tid] = (idx < N_ATOMS) ? deg[idx] : 0;
    __syncthreads();
    #pragma unroll
    for (int s = 128; s > 0; s >>= 1) {
        if (tid < s) sh[tid] += sh[tid + s];
        __syncthreads();
    }
    if (tid == 0) part[blockIdx.x] = sh[0];
}

__global__ __launch_bounds__(256) void scan_top_kernel(int* __restrict__ part)
{
    __shared__ int sh[256];
    int tid = threadIdx.x;
    int v = (tid < SCAN_BLOCKS) ? part[tid] : 0;
    sh[tid] = v;
    __syncthreads();
    #pragma unroll
    for (int off = 1; off < 256; off <<= 1) {
        int t = sh[tid];
        int add = (tid >= off) ? sh[tid - off] : 0;
        __syncthreads();
        sh[tid] = t + add;
        __syncthreads();
    }
    if (tid < SCAN_BLOCKS) part[tid] = sh[tid] - v;   // exclusive
}

__global__ __launch_bounds__(256) void scan_emit_kernel(const int* __restrict__ deg,
                                                        const int* __restrict__ part,
                                                        int* __restrict__ offs,
                                                        int* __restrict__ cursor)
{
    __shared__ int sh[256];
    int tid = threadIdx.x;
    int idx = blockIdx.x * 256 + tid;
    int v = (idx < N_ATOMS) ? deg[idx] : 0;
    sh[tid] = v;
    __syncthreads();
    #pragma unroll
    for (int off = 1; off < 256; off <<= 1) {
        int t = sh[tid];
        int add = (tid >= off) ? sh[tid - off] : 0;
        __syncthreads();
        sh[tid] = t + add;
        __syncthreads();
    }
    int excl = sh[tid] - v + part[blockIdx.x];
    if (idx < N_ATOMS) { offs[idx] = excl; cursor[idx] = excl; }
    if (idx == N_ATOMS - 1) offs[N_ATOMS] = 2 * N_BONDS;
}

__global__ void fill_kernel(const int* __restrict__ bonds, int* __restrict__ cursor,
                            int* __restrict__ adj)
{
    int e = blockIdx.x * blockDim.x + threadIdx.x;
    if (e >= N_BONDS) return;
    int a = bonds[2*e], b = bonds[2*e + 1];
    adj[atomicAdd(cursor + b, 1)] = a;
    adj[atomicAdd(cursor + a, 1)] = b;
}

// fused gather + mean + affine + residual: h_out = h_in + M*mean_nb(h_in)+c
__global__ void gather_kernel(const int* __restrict__ offs, const int* __restrict__ adj,
                              const float* __restrict__ mc, const float* __restrict__ upd_b,
                              const float* __restrict__ h_in, float* __restrict__ h_out)
{
    int t = blockIdx.x * blockDim.x + threadIdx.x;
    if (t >= N_ATOMS * BATCH) return;
    int n = t >> 4, b = t & 15;
    int o0 = offs[n], o1 = offs[n + 1];
    int base = n * 48 + b * 3;
    float d0, d1, d2;
    if (o1 > o0) {
        float s0 = 0.f, s1 = 0.f, s2 = 0.f;
        for (int j = o0; j < o1; ++j) {
            const float* hs = h_in + adj[j] * 48 + b * 3;
            s0 += hs[0]; s1 += hs[1]; s2 += hs[2];
        }
        float inv = 1.f / (float)(o1 - o0);
        s0 *= inv; s1 *= inv; s2 *= inv;
        d0 = mc[9]  + mc[0]*s0 + mc[1]*s1 + mc[2]*s2;
        d1 = mc[10] + mc[3]*s0 + mc[4]*s1 + mc[5]*s2;
        d2 = mc[11] + mc[6]*s0 + mc[7]*s1 + mc[8]*s2;
    } else {
        d0 = upd_b[0]; d1 = upd_b[1]; d2 = upd_b[2];
    }
    h_out[base]     = h_in[base]     + d0;
    h_out[base + 1] = h_in[base + 1] + d1;
    h_out[base + 2] = h_in[base + 2] + d2;
}

// ================= fallback (round-1) graph kernels =================
__global__ void degf_kernel(const int* __restrict__ bonds, float* __restrict__ deg)
{
    int e = blockIdx.x * blockDim.x + threadIdx.x;
    if (e >= N_BONDS) return;
    atomicAdd(deg + bonds[2*e],     1.f);
    atomicAdd(deg + bonds[2*e + 1], 1.f);
}

__global__ void scatter_kernel(const int* __restrict__ bonds,
                               const float* __restrict__ h_t, float* __restrict__ nb_t)
{
    int t = blockIdx.x * 192 + threadIdx.x;
    int e = t / 48, c = t % 48;
    if (e >= N_BONDS) return;
    int a  = bonds[2*e];
    int bb = bonds[2*e + 1];
    float va = h_t[a  * 48 + c];
    float vb = h_t[bb * 48 + c];
    atomicAdd(nb_t + bb * 48 + c, va);
    atomicAdd(nb_t + a  * 48 + c, vb);
}

__global__ void update_kernel(const float* __restrict__ nb_t, const float* __restrict__ deg,
                              const float* __restrict__ mc, const float* __restrict__ upd_b,
                              float* __restrict__ h_t)
{
    int t = blockIdx.x * blockDim.x + threadIdx.x;
    if (t >= N_ATOMS * BATCH) return;
    int n = t >> 4;
    int base = n * 48 + (t & 15) * 3;
    float dg = deg[n];
    float d0, d1, d2;
    if (dg > 0.f) {
        float inv = 1.f / dg;
        float m0 = nb_t[base] * inv, m1 = nb_t[base+1] * inv, m2 = nb_t[base+2] * inv;
        d0 = mc[9]  + mc[0]*m0 + mc[1]*m1 + mc[2]*m2;
        d1 = mc[10] + mc[3]*m0 + mc[4]*m1 + mc[5]*m2;
        d2 = mc[11] + mc[6]*m0 + mc[7]*m1 + mc[8]*m2;
    } else {
        d0 = upd_b[0]; d1 = upd_b[1]; d2 = upd_b[2];
    }
    h_t[base]     += d0;
    h_t[base + 1] += d1;
    h_t[base + 2] += d2;
}

// ---------------- fused output: standard GEMM + b_out + go-affine(h) ----------------
// 1 wave per block; x staged in LDS (broadcast reads); w row double-buffered in regs.
__global__ __launch_bounds__(64) void out_kernel(
    const float* __restrict__ w_out, const float* __restrict__ b_out,
    const float* __restrict__ x, const float* __restrict__ h_t,
    const float* __restrict__ go_w, const float* __restrict__ go_b,
    float* __restrict__ out)
{
    __shared__ float4 xs[1024];                 // [b][k4], 16 KiB
    const int tid = threadIdx.x;
    const float4* xv = reinterpret_cast<const float4*>(x);
    #pragma unroll
    for (int i = 0; i < 16; ++i) xs[tid + i * 64] = xv[tid + i * 64];
    __syncthreads();

    const int r = blockIdx.x * 64 + tid;
    if (r >= N3) return;
    const float4* wr = reinterpret_cast<const float4*>(w_out + (size_t)r * 256);

    float acc[16];
    #pragma unroll
    for (int b = 0; b < 16; ++b) acc[b] = 0.f;

    float4 wbuf[4];
    #pragma unroll
    for (int i = 0; i < 4; ++i) wbuf[i] = wr[i];

    #pragma unroll 1
    for (int c = 0; c < 16; ++c) {
        float4 wcur[4];
        #pragma unroll
        for (int i = 0; i < 4; ++i) wcur[i] = wbuf[i];
        if (c < 15) {
            #pragma unroll
            for (int i = 0; i < 4; ++i) wbuf[i] = wr[(c + 1) * 4 + i];
        }
        #pragma unroll
        for (int i = 0; i < 4; ++i) {
            const int k4 = c * 4 + i;
            #pragma unroll
            for (int b = 0; b < 16; ++b) {
                float4 xf = xs[b * 64 + k4];
                acc[b] += wcur[i].x * xf.x + wcur[i].y * xf.y
                        + wcur[i].z * xf.z + wcur[i].w * xf.w;
            }
        }
    }

    const int n = r / 3, d = r - 3 * n;
    const float g0 = go_w[d*3 + 0], g1 = go_w[d*3 + 1], g2 = go_w[d*3 + 2];
    const float gb = go_b[d] + b_out[r];
    const float* hb = h_t + n * 48;
    #pragma unroll
    for (int b = 0; b < 16; ++b) {
        float g = gb + g0 * hb[b*3] + g1 * hb[b*3 + 1] + g2 * hb[b*3 + 2];
        out[b * N3 + r] = acc[b] + g;
    }
}

extern "C" void kernel_launch(void* const* d_in, const int* in_sizes, int n_in,
                              void* d_out, int out_size, void* d_ws, size_t ws_size,
                              hipStream_t stream)
{
    const float* alpha = (const float*)d_in[0];
    const float* pos   = (const float*)d_in[1];
    const int*   bonds = (const int*)  d_in[2];
    const float* w_in  = (const float*)d_in[3];
    const float* b_in  = (const float*)d_in[4];
    const float* w1a   = (const float*)d_in[5];
    const float* b1a   = (const float*)d_in[6];
    const float* w1b   = (const float*)d_in[7];
    const float* b1b   = (const float*)d_in[8];
    const float* w2a   = (const float*)d_in[9];
    const float* b2a   = (const float*)d_in[10];
    const float* w2b   = (const float*)d_in[11];
    const float* b2b   = (const float*)d_in[12];
    const float* w_out = (const float*)d_in[13];
    const float* b_out = (const float*)d_in[14];
    const float* msg_w = (const float*)d_in[15];
    const float* msg_b = (const float*)d_in[16];
    const float* upd_w = (const float*)d_in[17];
    const float* upd_b = (const float*)d_in[18];
    const float* go_w  = (const float*)d_in[19];
    const float* go_b  = (const float*)d_in[20];

    float* out = (float*)d_out;
    float* ws  = (float*)d_ws;
    float* x   = ws + X_OFF;
    float* mc  = ws + MC_OFF;

    mlp_head_kernel<<<16, 256, 0, stream>>>(alpha, w_in, b_in,
                                            w1a, b1a, w1b, b1b,
                                            w2a, b2a, w2b, b2b, x);
    mc_kernel<<<1, 64, 0, stream>>>(msg_w, msg_b, upd_w, upd_b, mc);

    float* h_final;
    if (ws_size >= WS_FAST_BYTES) {
        // -------- CSR fast path --------
        int*   deg_i  = (int*)(ws + DEGI_OFF);
        int*   offs   = (int*)(ws + OFFS_OFF);
        int*   cursor = (int*)(ws + CUR_OFF);
        int*   part   = (int*)(ws + PART_OFF);
        int*   adj    = (int*)(ws + ADJ_OFF);
        float* hA     = ws + HA_OFF;
        float* hB     = ws + HB_OFF;

        hipMemsetAsync(deg_i, 0, N_ATOMS * sizeof(int), stream);
        degi_kernel<<<(N_BONDS + 255) / 256, 256, 0, stream>>>(bonds, deg_i);
        scan_part_kernel<<<SCAN_BLOCKS, 256, 0, stream>>>(deg_i, part);
        scan_top_kernel<<<1, 256, 0, stream>>>(part);
        scan_emit_kernel<<<SCAN_BLOCKS, 256, 0, stream>>>(deg_i, part, offs, cursor);
        fill_kernel<<<(N_BONDS + 255) / 256, 256, 0, stream>>>(bonds, cursor, adj);
        transpose_in_kernel<<<(N_ATOMS * 48 + 255) / 256, 256, 0, stream>>>(pos, hA);

        gather_kernel<<<(N_ATOMS * BATCH + 255) / 256, 256, 0, stream>>>(offs, adj, mc, upd_b, hA, hB);
        gather_kernel<<<(N_ATOMS * BATCH + 255) / 256, 256, 0, stream>>>(offs, adj, mc, upd_b, hB, hA);
        h_final = hA;
    } else {
        // -------- fallback: round-1 atomic scatter path --------
        float* degf = ws + DEGF_OFF;
        float* h_t  = ws + HT_OFF;
        size_t need_full = (size_t)(NB_OFF + N_ATOMS * 48) * sizeof(float);
        float* nb_t = (ws_size >= need_full) ? (ws + NB_OFF) : out;

        hipMemsetAsync(degf, 0, N_ATOMS * sizeof(float), stream);
        degf_kernel<<<(N_BONDS + 255) / 256, 256, 0, stream>>>(bonds, degf);
        transpose_in_kernel<<<(N_ATOMS * 48 + 255) / 256, 256, 0, stream>>>(pos, h_t);
        for (int it = 0; it < 2; ++it) {
            hipMemsetAsync(nb_t, 0, (size_t)N_ATOMS * 48 * sizeof(float), stream);
            scatter_kernel<<<25000, 192, 0, stream>>>(bonds, h_t, nb_t);
            update_kernel<<<(N_ATOMS * BATCH + 255) / 256, 256, 0, stream>>>(nb_t, degf, mc, upd_b, h_t);
        }
        h_final = h_t;
    }

    out_kernel<<<(N3 + 63) / 64, 64, 0, stream>>>(w_out, b_out, x, h_final, go_w, go_b, out);
}

// Round 4
// 148.886 us; speedup vs baseline: 1.9084x; 1.0916x over previous
//
#include <hip/hip_runtime.h>

#define N_ATOMS 50000
#define N_BONDS 100000
#define BATCH   16
#define N3      150000   // N_ATOMS*3

#define SCAN_BLOCKS ((N_ATOMS + 255) / 256)   // 196

// ---- fast-path workspace layout (4-byte element offsets) ----
#define X_OFF    0            // 4096 floats
#define MC_OFF   4096         // 16 floats (M 9, c 3)
#define DEGI_OFF 4112         // 50000 ints
#define OFFS_OFF 54112        // 50001 ints (+pad to 50016)
#define CUR_OFF  104128       // 50000 ints
#define PART_OFF 154128       // 256 ints
#define ADJ_OFF  154384       // 200000 ints
#define HA_OFF   354384       // 2,400,000 floats
#define HB_OFF   2754384      // 2,400,000 floats
#define WS_FAST_BYTES ((size_t)(HB_OFF + 2400000) * 4)

// ---- fallback layout ----
#define DEGF_OFF 4112         // 50000 floats
#define HT_OFF   54144        // 2,400,000 floats
#define NB_OFF   2454144      // 2,400,000 floats (optional in ws)

// ---------------- generic zero kernel (int4 granularity) ----------------
__global__ void zero4_kernel(int4* __restrict__ p, int n4)
{
    int t = blockIdx.x * 256 + threadIdx.x;
    if (t < n4) p[t] = make_int4(0, 0, 0, 0);
}

// ---------------- tiny MLP head: x[16][256]; block 16 computes mc ----------------
__global__ void mlp_head_kernel(const float* __restrict__ alpha,
    const float* __restrict__ w_in, const float* __restrict__ b_in,
    const float* __restrict__ w1a, const float* __restrict__ b1a,
    const float* __restrict__ w1b, const float* __restrict__ b1b,
    const float* __restrict__ w2a, const float* __restrict__ b2a,
    const float* __restrict__ w2b, const float* __restrict__ b2b,
    const float* __restrict__ msg_w, const float* __restrict__ msg_b,
    const float* __restrict__ upd_w, const float* __restrict__ upd_b,
    float* __restrict__ x_out, float* __restrict__ mc)
{
    const int b = blockIdx.x;
    const int j = threadIdx.x;

    if (b == 16) {   // collapse msg->upd into 3x3 affine: M (9), c (3)
        if (j < 9) {
            int d = j / 3, dp = j % 3;
            float s = 0.f;
            for (int k = 0; k < 128; ++k) s += upd_w[d*128 + k] * msg_w[k*3 + dp];
            mc[j] = s;
        } else if (j < 12) {
            int d = j - 9;
            float s = upd_b[d];
            for (int k = 0; k < 128; ++k) s += upd_w[d*128 + k] * msg_b[k];
            mc[9 + d] = s;
        }
        return;
    }

    __shared__ float xs[256];
    __shared__ float ts[256];

    float v = fmaxf(w_in[j] * alpha[b] + b_in[j], 0.f);
    xs[j] = v;
    __syncthreads();

    {   // ResBlock 1
        float acc = b1a[j];
        const float4* wr = reinterpret_cast<const float4*>(w1a + j * 256);
        #pragma unroll 8
        for (int k4 = 0; k4 < 64; ++k4) {
            float4 w = wr[k4];
            acc += w.x * xs[4*k4] + w.y * xs[4*k4+1] + w.z * xs[4*k4+2] + w.w * xs[4*k4+3];
        }
        ts[j] = fmaxf(acc, 0.f);
        __syncthreads();

        acc = b1b[j] + xs[j];
        wr = reinterpret_cast<const float4*>(w1b + j * 256);
        #pragma unroll 8
        for (int k4 = 0; k4 < 64; ++k4) {
            float4 w = wr[k4];
            acc += w.x * ts[4*k4] + w.y * ts[4*k4+1] + w.z * ts[4*k4+2] + w.w * ts[4*k4+3];
        }
        v = fmaxf(acc, 0.f);
        __syncthreads();
        xs[j] = v;
        __syncthreads();
    }
    {   // ResBlock 2
        float acc = b2a[j];
        const float4* wr = reinterpret_cast<const float4*>(w2a + j * 256);
        #pragma unroll 8
        for (int k4 = 0; k4 < 64; ++k4) {
            float4 w = wr[k4];
            acc += w.x * xs[4*k4] + w.y * xs[4*k4+1] + w.z * xs[4*k4+2] + w.w * xs[4*k4+3];
        }
        ts[j] = fmaxf(acc, 0.f);
        __syncthreads();

        acc = b2b[j] + xs[j];
        wr = reinterpret_cast<const float4*>(w2b + j * 256);
        #pragma unroll 8
        for (int k4 = 0; k4 < 64; ++k4) {
            float4 w = wr[k4];
            acc += w.x * ts[4*k4] + w.y * ts[4*k4+1] + w.z * ts[4*k4+2] + w.w * ts[4*k4+3];
        }
        v = fmaxf(acc, 0.f);
    }
    x_out[b * 256 + j] = v;
}

// -------- transpose positions (b,n,d) -> h[n][b*3+d]; optionally zero deg --------
__global__ void transpose_in_kernel(const float* __restrict__ pos, float* __restrict__ h_t,
                                    int4* __restrict__ deg_zero)   // may be nullptr
{
    int t = blockIdx.x * blockDim.x + threadIdx.x;
    if (deg_zero && t < N_ATOMS / 4) deg_zero[t] = make_int4(0, 0, 0, 0);
    if (t >= N_ATOMS * 48) return;
    int n = t / 48, c = t % 48;
    int b = c / 3, d = c % 3;
    h_t[t] = pos[(b * N_ATOMS + n) * 3 + d];
}

// ================= CSR build =================
__global__ void degi_kernel(const int* __restrict__ bonds, int* __restrict__ deg)
{
    int e = blockIdx.x * blockDim.x + threadIdx.x;
    if (e >= N_BONDS) return;
    atomicAdd(deg + bonds[2*e],     1);
    atomicAdd(deg + bonds[2*e + 1], 1);
}

__global__ __launch_bounds__(256) void scan_part_kernel(const int* __restrict__ deg,
                                                        int* __restrict__ part)
{
    __shared__ int sh[256];
    int tid = threadIdx.x;
    int idx = blockIdx.x * 256 + tid;
    sh[tid] = (idx < N_ATOMS) ? deg[idx] : 0;
    __syncthreads();
    #pragma unroll
    for (int s = 128; s > 0; s >>= 1) {
        if (tid < s) sh[tid] += sh[tid + s];
        __syncthreads();
    }
    if (tid == 0) part[blockIdx.x] = sh[0];
}

__global__ __launch_bounds__(256) void scan_top_kernel(int* __restrict__ part)
{
    __shared__ int sh[256];
    int tid = threadIdx.x;
    int v = (tid < SCAN_BLOCKS) ? part[tid] : 0;
    sh[tid] = v;
    __syncthreads();
    #pragma unroll
    for (int off = 1; off < 256; off <<= 1) {
        int t = sh[tid];
        int add = (tid >= off) ? sh[tid - off] : 0;
        __syncthreads();
        sh[tid] = t + add;
        __syncthreads();
    }
    if (tid < SCAN_BLOCKS) part[tid] = sh[tid] - v;   // exclusive
}

__global__ __launch_bounds__(256) void scan_emit_kernel(const int* __restrict__ deg,
                                                        const int* __restrict__ part,
                                                        int* __restrict__ offs,
                                                        int* __restrict__ cursor)
{
    __shared__ int sh[256];
    int tid = threadIdx.x;
    int idx = blockIdx.x * 256 + tid;
    int v = (idx < N_ATOMS) ? deg[idx] : 0;
    sh[tid] = v;
    __syncthreads();
    #pragma unroll
    for (int off = 1; off < 256; off <<= 1) {
        int t = sh[tid];
        int add = (tid >= off) ? sh[tid - off] : 0;
        __syncthreads();
        sh[tid] = t + add;
        __syncthreads();
    }
    int excl = sh[tid] - v + part[blockIdx.x];
    if (idx < N_ATOMS) { offs[idx] = excl; cursor[idx] = excl; }
    if (idx == N_ATOMS - 1) offs[N_ATOMS] = 2 * N_BONDS;
}

__global__ void fill_kernel(const int* __restrict__ bonds, int* __restrict__ cursor,
                            int* __restrict__ adj)
{
    int e = blockIdx.x * blockDim.x + threadIdx.x;
    if (e >= N_BONDS) return;
    int a = bonds[2*e], b = bonds[2*e + 1];
    adj[atomicAdd(cursor + b, 1)] = a;
    adj[atomicAdd(cursor + a, 1)] = b;
}

// fused gather + mean + affine + residual: h_out = h_in + M*mean_nb(h_in)+c
__global__ void gather_kernel(const int* __restrict__ offs, const int* __restrict__ adj,
                              const float* __restrict__ mc, const float* __restrict__ upd_b,
                              const float* __restrict__ h_in, float* __restrict__ h_out)
{
    int t = blockIdx.x * blockDim.x + threadIdx.x;
    if (t >= N_ATOMS * BATCH) return;
    int n = t >> 4, b = t & 15;
    int o0 = offs[n], o1 = offs[n + 1];
    int base = n * 48 + b * 3;
    float d0, d1, d2;
    if (o1 > o0) {
        float s0 = 0.f, s1 = 0.f, s2 = 0.f;
        for (int j = o0; j < o1; ++j) {
            const float* hs = h_in + adj[j] * 48 + b * 3;
            s0 += hs[0]; s1 += hs[1]; s2 += hs[2];
        }
        float inv = 1.f / (float)(o1 - o0);
        s0 *= inv; s1 *= inv; s2 *= inv;
        d0 = mc[9]  + mc[0]*s0 + mc[1]*s1 + mc[2]*s2;
        d1 = mc[10] + mc[3]*s0 + mc[4]*s1 + mc[5]*s2;
        d2 = mc[11] + mc[6]*s0 + mc[7]*s1 + mc[8]*s2;
    } else {
        d0 = upd_b[0]; d1 = upd_b[1]; d2 = upd_b[2];
    }
    h_out[base]     = h_in[base]     + d0;
    h_out[base + 1] = h_in[base + 1] + d1;
    h_out[base + 2] = h_in[base + 2] + d2;
}

// ================= fallback graph kernels =================
__global__ void degf_kernel(const int* __restrict__ bonds, float* __restrict__ deg)
{
    int e = blockIdx.x * blockDim.x + threadIdx.x;
    if (e >= N_BONDS) return;
    atomicAdd(deg + bonds[2*e],     1.f);
    atomicAdd(deg + bonds[2*e + 1], 1.f);
}

__global__ void scatter_kernel(const int* __restrict__ bonds,
                               const float* __restrict__ h_t, float* __restrict__ nb_t)
{
    int t = blockIdx.x * 192 + threadIdx.x;
    int e = t / 48, c = t % 48;
    if (e >= N_BONDS) return;
    int a  = bonds[2*e];
    int bb = bonds[2*e + 1];
    float va = h_t[a  * 48 + c];
    float vb = h_t[bb * 48 + c];
    atomicAdd(nb_t + bb * 48 + c, va);
    atomicAdd(nb_t + a  * 48 + c, vb);
}

__global__ void update_kernel(const float* __restrict__ nb_t, const float* __restrict__ deg,
                              const float* __restrict__ mc, const float* __restrict__ upd_b,
                              float* __restrict__ h_t)
{
    int t = blockIdx.x * blockDim.x + threadIdx.x;
    if (t >= N_ATOMS * BATCH) return;
    int n = t >> 4;
    int base = n * 48 + (t & 15) * 3;
    float dg = deg[n];
    float d0, d1, d2;
    if (dg > 0.f) {
        float inv = 1.f / dg;
        float m0 = nb_t[base] * inv, m1 = nb_t[base+1] * inv, m2 = nb_t[base+2] * inv;
        d0 = mc[9]  + mc[0]*m0 + mc[1]*m1 + mc[2]*m2;
        d1 = mc[10] + mc[3]*m0 + mc[4]*m1 + mc[5]*m2;
        d2 = mc[11] + mc[6]*m0 + mc[7]*m1 + mc[8]*m2;
    } else {
        d0 = upd_b[0]; d1 = upd_b[1]; d2 = upd_b[2];
    }
    h_t[base]     += d0;
    h_t[base + 1] += d1;
    h_t[base + 2] += d2;
}

// ---------------- fused output: standard GEMM + b_out + go-affine(h) ----------------
// 1 wave per block; each thread computes 2 rows x 16 batches: halves LDS-read
// pressure per FMA (one x ds_read feeds 2 rows). x staged in LDS (broadcast).
__global__ __launch_bounds__(64) void out_kernel(
    const float* __restrict__ w_out, const float* __restrict__ b_out,
    const float* __restrict__ x, const float* __restrict__ h_t,
    const float* __restrict__ go_w, const float* __restrict__ go_b,
    float* __restrict__ out)
{
    __shared__ float4 xs[1024];                 // [b][k4], 16 KiB
    const int tid = threadIdx.x;
    const float4* xv = reinterpret_cast<const float4*>(x);
    #pragma unroll
    for (int i = 0; i < 16; ++i) xs[tid + i * 64] = xv[tid + i * 64];
    __syncthreads();

    const int r0 = blockIdx.x * 128 + tid;      // r0 <= 149951 < N3 always
    const int r1 = r0 + 64;
    const bool v1 = (r1 < N3);
    const int r1c = v1 ? r1 : r0;

    const float4* wr0 = reinterpret_cast<const float4*>(w_out + (size_t)r0 * 256);
    const float4* wr1 = reinterpret_cast<const float4*>(w_out + (size_t)r1c * 256);

    float acc0[16], acc1[16];
    #pragma unroll
    for (int b = 0; b < 16; ++b) { acc0[b] = 0.f; acc1[b] = 0.f; }

    float4 wbuf0[4], wbuf1[4];
    #pragma unroll
    for (int i = 0; i < 4; ++i) { wbuf0[i] = wr0[i]; wbuf1[i] = wr1[i]; }

    #pragma unroll 1
    for (int c = 0; c < 16; ++c) {
        float4 wc0[4], wc1[4];
        #pragma unroll
        for (int i = 0; i < 4; ++i) { wc0[i] = wbuf0[i]; wc1[i] = wbuf1[i]; }
        if (c < 15) {
            #pragma unroll
            for (int i = 0; i < 4; ++i) {
                wbuf0[i] = wr0[(c + 1) * 4 + i];
                wbuf1[i] = wr1[(c + 1) * 4 + i];
            }
        }
        #pragma unroll
        for (int i = 0; i < 4; ++i) {
            const int k4 = c * 4 + i;
            #pragma unroll
            for (int b = 0; b < 16; ++b) {
                float4 xf = xs[b * 64 + k4];
                acc0[b] += wc0[i].x * xf.x + wc0[i].y * xf.y
                         + wc0[i].z * xf.z + wc0[i].w * xf.w;
                acc1[b] += wc1[i].x * xf.x + wc1[i].y * xf.y
                         + wc1[i].z * xf.z + wc1[i].w * xf.w;
            }
        }
    }

    {
        const int n = r0 / 3, d = r0 - 3 * n;
        const float g0 = go_w[d*3], g1 = go_w[d*3 + 1], g2 = go_w[d*3 + 2];
        const float gb = go_b[d] + b_out[r0];
        const float* hb = h_t + n * 48;
        #pragma unroll
        for (int b = 0; b < 16; ++b) {
            float g = gb + g0 * hb[b*3] + g1 * hb[b*3 + 1] + g2 * hb[b*3 + 2];
            out[b * N3 + r0] = acc0[b] + g;
        }
    }
    if (v1) {
        const int n = r1 / 3, d = r1 - 3 * n;
        const float g0 = go_w[d*3], g1 = go_w[d*3 + 1], g2 = go_w[d*3 + 2];
        const float gb = go_b[d] + b_out[r1];
        const float* hb = h_t + n * 48;
        #pragma unroll
        for (int b = 0; b < 16; ++b) {
            float g = gb + g0 * hb[b*3] + g1 * hb[b*3 + 1] + g2 * hb[b*3 + 2];
            out[b * N3 + r1] = acc1[b] + g;
        }
    }
}

extern "C" void kernel_launch(void* const* d_in, const int* in_sizes, int n_in,
                              void* d_out, int out_size, void* d_ws, size_t ws_size,
                              hipStream_t stream)
{
    const float* alpha = (const float*)d_in[0];
    const float* pos   = (const float*)d_in[1];
    const int*   bonds = (const int*)  d_in[2];
    const float* w_in  = (const float*)d_in[3];
    const float* b_in  = (const float*)d_in[4];
    const float* w1a   = (const float*)d_in[5];
    const float* b1a   = (const float*)d_in[6];
    const float* w1b   = (const float*)d_in[7];
    const float* b1b   = (const float*)d_in[8];
    const float* w2a   = (const float*)d_in[9];
    const float* b2a   = (const float*)d_in[10];
    const float* w2b   = (const float*)d_in[11];
    const float* b2b   = (const float*)d_in[12];
    const float* w_out = (const float*)d_in[13];
    const float* b_out = (const float*)d_in[14];
    const float* msg_w = (const float*)d_in[15];
    const float* msg_b = (const float*)d_in[16];
    const float* upd_w = (const float*)d_in[17];
    const float* upd_b = (const float*)d_in[18];
    const float* go_w  = (const float*)d_in[19];
    const float* go_b  = (const float*)d_in[20];

    float* out = (float*)d_out;
    float* ws  = (float*)d_ws;
    float* x   = ws + X_OFF;
    float* mc  = ws + MC_OFF;

    mlp_head_kernel<<<17, 256, 0, stream>>>(alpha, w_in, b_in,
                                            w1a, b1a, w1b, b1b,
                                            w2a, b2a, w2b, b2b,
                                            msg_w, msg_b, upd_w, upd_b, x, mc);

    float* h_final;
    if (ws_size >= WS_FAST_BYTES) {
        // -------- CSR fast path (no runtime memsets anywhere) --------
        int*   deg_i  = (int*)(ws + DEGI_OFF);
        int*   offs   = (int*)(ws + OFFS_OFF);
        int*   cursor = (int*)(ws + CUR_OFF);
        int*   part   = (int*)(ws + PART_OFF);
        int*   adj    = (int*)(ws + ADJ_OFF);
        float* hA     = ws + HA_OFF;
        float* hB     = ws + HB_OFF;

        transpose_in_kernel<<<(N_ATOMS * 48 + 255) / 256, 256, 0, stream>>>(pos, hA, (int4*)deg_i);
        degi_kernel<<<(N_BONDS + 255) / 256, 256, 0, stream>>>(bonds, deg_i);
        scan_part_kernel<<<SCAN_BLOCKS, 256, 0, stream>>>(deg_i, part);
        scan_top_kernel<<<1, 256, 0, stream>>>(part);
        scan_emit_kernel<<<SCAN_BLOCKS, 256, 0, stream>>>(deg_i, part, offs, cursor);
        fill_kernel<<<(N_BONDS + 255) / 256, 256, 0, stream>>>(bonds, cursor, adj);

        gather_kernel<<<(N_ATOMS * BATCH + 255) / 256, 256, 0, stream>>>(offs, adj, mc, upd_b, hA, hB);
        gather_kernel<<<(N_ATOMS * BATCH + 255) / 256, 256, 0, stream>>>(offs, adj, mc, upd_b, hB, hA);
        h_final = hA;
    } else {
        // -------- fallback: atomic scatter path (kernel-based zeroing) --------
        float* degf = ws + DEGF_OFF;
        float* h_t  = ws + HT_OFF;
        size_t need_full = (size_t)(NB_OFF + N_ATOMS * 48) * sizeof(float);
        float* nb_t = (ws_size >= need_full) ? (ws + NB_OFF) : out;

        zero4_kernel<<<(N_ATOMS / 4 + 255) / 256, 256, 0, stream>>>((int4*)degf, N_ATOMS / 4);
        degf_kernel<<<(N_BONDS + 255) / 256, 256, 0, stream>>>(bonds, degf);
        transpose_in_kernel<<<(N_ATOMS * 48 + 255) / 256, 256, 0, stream>>>(pos, h_t, nullptr);
        for (int it = 0; it < 2; ++it) {
            zero4_kernel<<<(N_ATOMS * 48 / 4 + 255) / 256, 256, 0, stream>>>((int4*)nb_t, N_ATOMS * 48 / 4);
            scatter_kernel<<<25000, 192, 0, stream>>>(bonds, h_t, nb_t);
            update_kernel<<<(N_ATOMS * BATCH + 255) / 256, 256, 0, stream>>>(nb_t, degf, mc, upd_b, h_t);
        }
        h_final = h_t;
    }

    out_kernel<<<(N3 + 127) / 128, 64, 0, stream>>>(w_out, b_out, x, h_final, go_w, go_b, out);
}